// Round 1
// 374.576 us; speedup vs baseline: 1.0293x; 1.0293x over previous
//
#include <hip/hip_runtime.h>
#include <math.h>

// Sizes (fixed by the problem)
#define B_SZ 8
#define L_SZ 4096
#define D_SZ 1024
#define M_SZ 64
#define ROWS (B_SZ * L_SZ)   // 32768
#define NCHUNK 64            // L / CHUNK
#define CHUNK 64

#define FMA4(acc, sc, v) { (acc).x += (sc)*(v).x; (acc).y += (sc)*(v).y; (acc).z += (sc)*(v).z; (acc).w += (sc)*(v).w; }
#define SCALE4(v, sc) { (v).x *= (sc); (v).y *= (sc); (v).z *= (sc); (v).w *= (sc); }

typedef __attribute__((ext_vector_type(8))) short bf16x8;
typedef __attribute__((ext_vector_type(4))) float f32x4;

__device__ __forceinline__ float sigmoid_f(float z) { return 1.0f / (1.0f + __expf(-z)); }
__device__ __forceinline__ float decay_of(const float* __restrict__ dp) {
  return 0.9f + (0.999f - 0.9f) * sigmoid_f(dp[0]);
}
// fp32 -> bf16 round-to-nearest-even
__device__ __forceinline__ unsigned short f2bf(float f) {
  unsigned int u = __float_as_uint(f);
  unsigned int r = (u + 0x7FFFu + ((u >> 16) & 1u)) >> 16;
  return (unsigned short)r;
}

// ---------------- Kernel 0: weight prep ----------------
// Wt[n][k] = W*[k][n] in bf16; n: 0-63 = Wq cols, 64-127 = Wk, 128-191 = Wv.
__global__ __launch_bounds__(256) void k0_prep(
    const float* __restrict__ Wq, const float* __restrict__ Wk,
    const float* __restrict__ Wv, unsigned short* __restrict__ Wt)
{
  const int n = blockIdx.x;
  const float* src = (n < 64) ? Wq : (n < 128) ? Wk : Wv;
  const int nc = n & 63;
  #pragma unroll
  for (int j = 0; j < 4; ++j) {
    int k = threadIdx.x + 256 * j;
    Wt[(size_t)n * D_SZ + k] = f2bf(src[(size_t)k * 64 + nc]);
  }
}

// ---------------- Kernel 1: MFMA fused q,k,v,gate projection ----------------
// v2: latency-oriented restructure.
//  - 64 rows/block -> grid 512 -> 2 blocks/CU (8 waves/CU instead of 4).
//  - A (x) loaded direct global->reg per MFMA fragment (wave-private rows),
//    converted in-register; no LDS staging / no A sync.
//  - B double-buffered in LDS, software-pipelined one k-tile ahead:
//    issue loads(t+1) -> MFMA(t) -> ds_write(t+1) -> ONE barrier per k-step.
//    Loads stay in flight across the barrier (reg-staged T14/T3 pattern).
#define K1_ROWS 64
#define K1_LDB 72   // bf16 elems/row: 64 + 8 pad -> 144B rows (16B aligned, de-aliased banks)

__global__ __launch_bounds__(256, 2) void k1_qkvg_mfma(
    const float* __restrict__ x, const unsigned short* __restrict__ Wt,
    const float* __restrict__ Wg, const float* __restrict__ bg,
    float* __restrict__ q_ws, float* __restrict__ a_ws, float* __restrict__ b_ws)
{
  __shared__ __align__(16) unsigned short Bs[2][192 * K1_LDB];
  __shared__ float Wgs[D_SZ];

  const int tid  = threadIdx.x;
  const int lane = tid & 63;
  const int w    = tid >> 6;        // wave 0..3 -> rows 16w..16w+15
  const int quad = lane >> 4;
  const int l15  = lane & 15;
  const int row0 = blockIdx.x * K1_ROWS;

  const float* xrow = x + (size_t)(row0 + 16 * w + l15) * D_SZ;

  f32x4 acc[12];
  #pragma unroll
  for (int tn = 0; tn < 12; ++tn) acc[tn] = (f32x4){0.f, 0.f, 0.f, 0.f};

  uint4  bb[6];     // B tile staged in regs
  float4 xa[4];     // A fragment fp32 (2 kt x 8 floats)
  bf16x8 af[2];     // A fragment bf16
  float  gacc = 0.f;

  // Wg -> LDS once (gate dot reads are quad-uniform broadcasts)
  *reinterpret_cast<float4*>(&Wgs[4 * tid]) = *reinterpret_cast<const float4*>(Wg + 4 * tid);

  auto loadB = [&](int k0) {
    #pragma unroll
    for (int i = 0; i < 6; ++i) {
      int cid = tid + 256 * i;          // 0..1535 -> (n, 8k-chunk)
      int n = cid >> 3, c = cid & 7;
      bb[i] = *reinterpret_cast<const uint4*>(Wt + (size_t)n * D_SZ + k0 + 8 * c);
    }
  };
  auto loadA = [&](int k0) {
    #pragma unroll
    for (int kt = 0; kt < 2; ++kt)
      #pragma unroll
      for (int j = 0; j < 2; ++j)
        xa[kt * 2 + j] = *reinterpret_cast<const float4*>(xrow + k0 + kt * 32 + quad * 8 + 4 * j);
  };
  auto writeB = [&](int buf) {
    #pragma unroll
    for (int i = 0; i < 6; ++i) {
      int cid = tid + 256 * i;
      int n = cid >> 3, c = cid & 7;
      *reinterpret_cast<uint4*>(&Bs[buf][n * K1_LDB + 8 * c]) = bb[i];
    }
  };
  auto cvtA = [&](int k0) {
    #pragma unroll
    for (int kt = 0; kt < 2; ++kt) {
      float4 lo = xa[kt * 2], hi = xa[kt * 2 + 1];
      const float* wp = &Wgs[k0 + kt * 32 + quad * 8];
      float4 w0 = *reinterpret_cast<const float4*>(wp);
      float4 w1 = *reinterpret_cast<const float4*>(wp + 4);
      gacc += lo.x * w0.x + lo.y * w0.y + lo.z * w0.z + lo.w * w0.w
            + hi.x * w1.x + hi.y * w1.y + hi.z * w1.z + hi.w * w1.w;
      uint4 p;
      p.x = (unsigned)f2bf(lo.x) | ((unsigned)f2bf(lo.y) << 16);
      p.y = (unsigned)f2bf(lo.z) | ((unsigned)f2bf(lo.w) << 16);
      p.z = (unsigned)f2bf(hi.x) | ((unsigned)f2bf(hi.y) << 16);
      p.w = (unsigned)f2bf(hi.z) | ((unsigned)f2bf(hi.w) << 16);
      af[kt] = *reinterpret_cast<bf16x8*>(&p);
    }
  };

  // ---- prologue: tile 0 ----
  loadA(0); loadB(0);
  __syncthreads();          // Wgs visible
  writeB(0);
  cvtA(0);
  __syncthreads();          // Bs[0] visible

  // ---- main loop: one barrier per k-step, loads one tile ahead ----
  for (int t = 0; t < 16; ++t) {
    const int cur = t & 1;
    if (t < 15) { loadA((t + 1) * 64); loadB((t + 1) * 64); }
    #pragma unroll
    for (int tn = 0; tn < 12; ++tn) {
      bf16x8 b0 = *reinterpret_cast<bf16x8*>(&Bs[cur][(tn * 16 + l15) * K1_LDB + quad * 8]);
      bf16x8 b1 = *reinterpret_cast<bf16x8*>(&Bs[cur][(tn * 16 + l15) * K1_LDB + 32 + quad * 8]);
      acc[tn] = __builtin_amdgcn_mfma_f32_16x16x32_bf16(af[0], b0, acc[tn], 0, 0, 0);
      acc[tn] = __builtin_amdgcn_mfma_f32_16x16x32_bf16(af[1], b1, acc[tn], 0, 0, 0);
    }
    if (t < 15) {
      writeB(cur ^ 1);      // implicit vmcnt wait lands here, after the MFMAs
      cvtA((t + 1) * 64);
      __syncthreads();
    }
  }

  // ---- gate finalize: reduce over quads; every lane gets its l15-row's gate ----
  float g = gacc;
  g += __shfl_xor(g, 16);
  g += __shfl_xor(g, 32);
  const float gs = sigmoid_f(g + bg[0]);
  float gr[4];
  #pragma unroll
  for (int r = 0; r < 4; ++r) gr[r] = __shfl(gs, quad * 4 + r);

  // ---- epilogue: C row = 16w + quad*4 + r, col = (tn&3)*16 + l15 ----
  #pragma unroll
  for (int tn = 0; tn < 12; ++tn) {
    const int ncol = (tn & 3) * 16 + l15;
    float* dst = (tn < 4) ? q_ws : (tn < 8 ? a_ws : b_ws);
    #pragma unroll
    for (int r = 0; r < 4; ++r) {
      const int rl = 16 * w + quad * 4 + r;
      float vv = acc[tn][r];
      if (tn >= 4) vv *= gr[r];
      dst[(size_t)(row0 + rl) * 64 + ncol] = vv;
    }
  }
}

// ---------------- Kernel 2: per-chunk state delta ----------------
__global__ __launch_bounds__(256) void k2_delta(
    const float* __restrict__ a_ws, const float* __restrict__ b_ws,
    const float* __restrict__ dp, float* __restrict__ dS)
{
  __shared__ float Aa[64][64];
  __shared__ float Bc[64][64];
  __shared__ float pw[64];
  const int tid = threadIdx.x;
  const int bc = blockIdx.x;                       // b*64 + c
  const int rowbase = (bc >> 6) * L_SZ + (bc & 63) * CHUNK;
  const int s = tid >> 2, m0 = (tid & 3) * 16;
  #pragma unroll
  for (int j = 0; j < 4; ++j) {
    *reinterpret_cast<float4*>(&Aa[s][m0 + 4*j]) =
        *reinterpret_cast<const float4*>(&a_ws[(size_t)(rowbase + s) * 64 + m0 + 4*j]);
    *reinterpret_cast<float4*>(&Bc[s][m0 + 4*j]) =
        *reinterpret_cast<const float4*>(&b_ws[(size_t)(rowbase + s) * 64 + m0 + 4*j]);
  }
  if (tid < 64) pw[tid] = powf(decay_of(dp), (float)(63 - tid));
  __syncthreads();
  const int d0 = tid >> 2, e0 = (tid & 3) * 16;
  float4 o0 = make_float4(0,0,0,0), o1 = o0, o2 = o0, o3 = o0;
  for (int ss = 0; ss < 64; ++ss) {
    float wa = pw[ss] * Aa[ss][d0];
    float4 b0 = *reinterpret_cast<float4*>(&Bc[ss][e0+0]);
    float4 b1 = *reinterpret_cast<float4*>(&Bc[ss][e0+4]);
    float4 b2 = *reinterpret_cast<float4*>(&Bc[ss][e0+8]);
    float4 b3 = *reinterpret_cast<float4*>(&Bc[ss][e0+12]);
    FMA4(o0, wa, b0); FMA4(o1, wa, b1); FMA4(o2, wa, b2); FMA4(o3, wa, b3);
  }
  float* dst = &dS[((size_t)bc << 12) + d0 * 64 + e0];
  *reinterpret_cast<float4*>(dst + 0)  = o0;
  *reinterpret_cast<float4*>(dst + 4)  = o1;
  *reinterpret_cast<float4*>(dst + 8)  = o2;
  *reinterpret_cast<float4*>(dst + 12) = o3;
}

// ---------------- Kernel 3: elementwise scan over chunks ----------------
// v2: preload all 64 chunk deltas into registers (one exposed latency)
// before running the dependent recurrence.
__global__ __launch_bounds__(256) void k3_scan(
    const float* __restrict__ dS, const float* __restrict__ dp,
    float* __restrict__ Sst, float* __restrict__ sfin)
{
  const int g = blockIdx.x * 256 + threadIdx.x;   // 0..32767
  const int b = g >> 12;
  const int de = g & 4095;
  const float dC = powf(decay_of(dp), 64.0f);
  const size_t base = ((size_t)(b * 64) << 12) + de;
  float d[NCHUNK];
  #pragma unroll
  for (int c = 0; c < NCHUNK; ++c) d[c] = dS[base + ((size_t)c << 12)];
  float s = 0.f;
  #pragma unroll
  for (int c = 0; c < NCHUNK; ++c) {
    Sst[base + ((size_t)c << 12)] = s;
    s = dC * s + d[c];
  }
  sfin[((size_t)b << 12) + de] = s;
}

// ---------------- Kernel 4: intra-chunk outputs ----------------
__global__ __launch_bounds__(256) void k4_intra(
    const float* __restrict__ q_ws, const float* __restrict__ a_ws,
    const float* __restrict__ b_ws, const float* __restrict__ Sst,
    const float* __restrict__ dp, float* __restrict__ outs)
{
  __shared__ float Qs[64][68];   // padded (col reads)
  __shared__ float Ps[64][68];   // holds A^T during phase 1, then P
  __shared__ float Bs[64][64];
  __shared__ float S0s[64][64];
  __shared__ float pw[65];
  const int tid = threadIdx.x;
  const int bc = blockIdx.x;
  const int rowbase = (bc >> 6) * L_SZ + (bc & 63) * CHUNK;
  const int s = tid >> 2, m0 = (tid & 3) * 16;
  #pragma unroll
  for (int j = 0; j < 4; ++j) {
    float4 qv = *reinterpret_cast<const float4*>(&q_ws[(size_t)(rowbase + s) * 64 + m0 + 4*j]);
    Qs[s][m0+4*j+0] = qv.x; Qs[s][m0+4*j+1] = qv.y; Qs[s][m0+4*j+2] = qv.z; Qs[s][m0+4*j+3] = qv.w;
    float4 av = *reinterpret_cast<const float4*>(&a_ws[(size_t)(rowbase + s) * 64 + m0 + 4*j]);
    Ps[m0+4*j+0][s] = av.x; Ps[m0+4*j+1][s] = av.y; Ps[m0+4*j+2][s] = av.z; Ps[m0+4*j+3][s] = av.w;
    float4 bv = *reinterpret_cast<const float4*>(&b_ws[(size_t)(rowbase + s) * 64 + m0 + 4*j]);
    *reinterpret_cast<float4*>(&Bs[s][m0+4*j]) = bv;
    float4 sv = *reinterpret_cast<const float4*>(&Sst[((size_t)bc << 12) + tid*16 + 4*j]);
    *reinterpret_cast<float4*>(&(&S0s[0][0])[tid*16 + 4*j]) = sv;
  }
  if (tid < 65) pw[tid] = powf(decay_of(dp), (float)tid);
  __syncthreads();

  const int t0 = tid >> 2, c0 = (tid & 3) * 16;  // this thread: row t0, cols c0..c0+15
  float4 r0 = make_float4(0,0,0,0), r1 = r0, r2 = r0, r3 = r0;
  for (int m = 0; m < 64; ++m) {
    float qv = Qs[t0][m];
    float4 a0 = *reinterpret_cast<float4*>(&Ps[m][c0+0]);
    float4 a1 = *reinterpret_cast<float4*>(&Ps[m][c0+4]);
    float4 a2 = *reinterpret_cast<float4*>(&Ps[m][c0+8]);
    float4 a3 = *reinterpret_cast<float4*>(&Ps[m][c0+12]);
    FMA4(r0, qv, a0); FMA4(r1, qv, a1); FMA4(r2, qv, a2); FMA4(r3, qv, a3);
  }
  float rr[16] = {r0.x,r0.y,r0.z,r0.w, r1.x,r1.y,r1.z,r1.w,
                  r2.x,r2.y,r2.z,r2.w, r3.x,r3.y,r3.z,r3.w};
  __syncthreads();  // everyone done reading A^T
  #pragma unroll
  for (int j = 0; j < 16; ++j) {
    const int sidx = c0 + j;
    Ps[t0][sidx] = (sidx <= t0) ? rr[j] * pw[t0 - sidx] : 0.f;
  }
  __syncthreads();

  float4 o0 = make_float4(0,0,0,0), o1 = o0, o2 = o0, o3 = o0;
  for (int m = 0; m < 64; ++m) {
    float qv = Qs[t0][m];
    float4 v0 = *reinterpret_cast<float4*>(&S0s[m][c0+0]);
    float4 v1 = *reinterpret_cast<float4*>(&S0s[m][c0+4]);
    float4 v2 = *reinterpret_cast<float4*>(&S0s[m][c0+8]);
    float4 v3 = *reinterpret_cast<float4*>(&S0s[m][c0+12]);
    FMA4(o0, qv, v0); FMA4(o1, qv, v1); FMA4(o2, qv, v2); FMA4(o3, qv, v3);
  }
  const float dsc = pw[t0 + 1];
  SCALE4(o0, dsc); SCALE4(o1, dsc); SCALE4(o2, dsc); SCALE4(o3, dsc);
  for (int ss = 0; ss < 64; ++ss) {
    float pv = Ps[t0][ss];
    float4 b0 = *reinterpret_cast<float4*>(&Bs[ss][c0+0]);
    float4 b1 = *reinterpret_cast<float4*>(&Bs[ss][c0+4]);
    float4 b2 = *reinterpret_cast<float4*>(&Bs[ss][c0+8]);
    float4 b3 = *reinterpret_cast<float4*>(&Bs[ss][c0+12]);
    FMA4(o0, pv, b0); FMA4(o1, pv, b1); FMA4(o2, pv, b2); FMA4(o3, pv, b3);
  }
  float* dst = &outs[(size_t)(rowbase + t0) * 64 + c0];
  *reinterpret_cast<float4*>(dst + 0)  = o0;
  *reinterpret_cast<float4*>(dst + 4)  = o1;
  *reinterpret_cast<float4*>(dst + 8)  = o2;
  *reinterpret_cast<float4*>(dst + 12) = o3;
}

// ---------------- Kernel 5: output projection ----------------
__global__ __launch_bounds__(256) void k5_proj(
    const float* __restrict__ outs, const float* __restrict__ Wo,
    const float* __restrict__ bo, float* __restrict__ y)
{
  __shared__ float Os[64][68];
  __shared__ float Ws[64][64];
  const int tid = threadIdx.x;
  const int tx = tid & 15, ty = tid >> 4;
  const int row0 = blockIdx.x * 64;
  const int n0 = blockIdx.y * 64;
  const int s = tid >> 2, m0 = (tid & 3) * 16;
  #pragma unroll
  for (int j = 0; j < 4; ++j) {
    float4 ov = *reinterpret_cast<const float4*>(&outs[(size_t)(row0 + s) * 64 + m0 + 4*j]);
    Os[s][m0+4*j+0] = ov.x; Os[s][m0+4*j+1] = ov.y; Os[s][m0+4*j+2] = ov.z; Os[s][m0+4*j+3] = ov.w;
    float4 wv = *reinterpret_cast<const float4*>(&Wo[(size_t)s * D_SZ + n0 + m0 + 4*j]);
    *reinterpret_cast<float4*>(&Ws[s][m0+4*j]) = wv;
  }
  __syncthreads();
  float4 acc[4];
  #pragma unroll
  for (int r = 0; r < 4; ++r) acc[r] = make_float4(0,0,0,0);
  for (int kk = 0; kk < 64; ++kk) {
    float a0 = Os[4*ty+0][kk];
    float a1 = Os[4*ty+1][kk];
    float a2 = Os[4*ty+2][kk];
    float a3 = Os[4*ty+3][kk];
    float4 w = *reinterpret_cast<float4*>(&Ws[kk][4*tx]);
    FMA4(acc[0], a0, w); FMA4(acc[1], a1, w); FMA4(acc[2], a2, w); FMA4(acc[3], a3, w);
  }
  float4 bv = *reinterpret_cast<const float4*>(&bo[n0 + 4*tx]);
  #pragma unroll
  for (int r = 0; r < 4; ++r) {
    float4 res;
    res.x = acc[r].x + bv.x; res.y = acc[r].y + bv.y;
    res.z = acc[r].z + bv.z; res.w = acc[r].w + bv.w;
    *reinterpret_cast<float4*>(&y[(size_t)(row0 + 4*ty + r) * D_SZ + n0 + 4*tx]) = res;
  }
}

// ---------------- Launcher ----------------
extern "C" void kernel_launch(void* const* d_in, const int* in_sizes, int n_in,
                              void* d_out, int out_size, void* d_ws, size_t ws_size,
                              hipStream_t stream) {
  (void)in_sizes; (void)n_in; (void)out_size; (void)ws_size;
  const float* x  = (const float*)d_in[0];
  const float* Wq = (const float*)d_in[1];
  const float* Wk = (const float*)d_in[2];
  const float* Wv = (const float*)d_in[3];
  const float* Wo = (const float*)d_in[4];
  const float* bo = (const float*)d_in[5];
  const float* Wg = (const float*)d_in[6];
  const float* bg = (const float*)d_in[7];
  const float* dp = (const float*)d_in[8];

  float* y    = (float*)d_out;                       // (8,4096,1024)
  float* sfin = y + (size_t)B_SZ * L_SZ * D_SZ;      // (8,64,64)

  float* ws   = (float*)d_ws;
  const size_t SEG = (size_t)ROWS * M_SZ;            // 2,097,152 floats
  float* q_ws = ws;
  float* a_ws = q_ws + SEG;
  float* b_ws = a_ws + SEG;
  float* dS   = b_ws + SEG;   // (B*NC, 64,64)
  float* Sst  = dS   + SEG;   // chunk-start states
  float* outs = Sst  + SEG;   // (32768, 64)
  // Wt (bf16 192x1024 = 384KB) aliases the head of `outs`: dead after k1
  // reads it, before k4 writes outs. Rewritten every call (ws re-poisoned).
  unsigned short* Wt = (unsigned short*)outs;

  k0_prep<<<dim3(192), dim3(256), 0, stream>>>(Wq, Wk, Wv, Wt);
  k1_qkvg_mfma<<<dim3(ROWS / K1_ROWS), dim3(256), 0, stream>>>(x, Wt, Wg, bg, q_ws, a_ws, b_ws);
  k2_delta<<<dim3(B_SZ * NCHUNK), dim3(256), 0, stream>>>(a_ws, b_ws, dp, dS);
  k3_scan<<<dim3((B_SZ * M_SZ * M_SZ) / 256), dim3(256), 0, stream>>>(dS, dp, Sst, sfin);
  k4_intra<<<dim3(B_SZ * NCHUNK), dim3(256), 0, stream>>>(q_ws, a_ws, b_ws, Sst, dp, outs);
  k5_proj<<<dim3(ROWS / 64, D_SZ / 64), dim3(256), 0, stream>>>(outs, Wo, bo, y);
}

// Round 3
// 358.504 us; speedup vs baseline: 1.0755x; 1.0448x over previous
//
#include <hip/hip_runtime.h>
#include <math.h>

// Sizes (fixed by the problem)
#define B_SZ 8
#define L_SZ 4096
#define D_SZ 1024
#define M_SZ 64
#define ROWS (B_SZ * L_SZ)   // 32768
#define NCHUNK 64            // L / CHUNK
#define CHUNK 64

#define FMA4(acc, sc, v) { (acc).x += (sc)*(v).x; (acc).y += (sc)*(v).y; (acc).z += (sc)*(v).z; (acc).w += (sc)*(v).w; }
#define SCALE4(v, sc) { (v).x *= (sc); (v).y *= (sc); (v).z *= (sc); (v).w *= (sc); }

typedef __attribute__((ext_vector_type(8))) short bf16x8;
typedef __attribute__((ext_vector_type(4))) float f32x4;

__device__ __forceinline__ float sigmoid_f(float z) { return 1.0f / (1.0f + __expf(-z)); }
__device__ __forceinline__ float decay_of(const float* __restrict__ dp) {
  return 0.9f + (0.999f - 0.9f) * sigmoid_f(dp[0]);
}
// fp32 -> bf16 round-to-nearest-even
__device__ __forceinline__ unsigned short f2bf(float f) {
  unsigned int u = __float_as_uint(f);
  unsigned int r = (u + 0x7FFFu + ((u >> 16) & 1u)) >> 16;
  return (unsigned short)r;
}

// async global->LDS, 16B per lane. HW: wave-uniform LDS base + lane*16;
// per-lane GLOBAL source. All call sites keep waves fully active.
__device__ __forceinline__ void gl2lds16(const void* g, void* l) {
  __builtin_amdgcn_global_load_lds(
      (const __attribute__((address_space(1))) unsigned int*)g,
      (__attribute__((address_space(3))) unsigned int*)l, 16, 0, 0);
}

// ---------------- Kernel 0: weight prep ----------------
// Wt laid out EXACTLY in k1's staged order: [kt 0..15][n 0..207][chunk 0..8][8 bf16],
// each kt-slice padded to 1920 16B-chunks (30720B = 7.5*256 chunks) so k1 stages
// with fully-active waves only.
// n: 0-63 Wq cols, 64-127 Wk, 128-191 Wv, 192 Wg, 193-207 zero. chunk 8 = row pad.
#define BT_CH     1872        // real chunks per kt-slice (208*9)
#define BT_CH_PAD 1920        // padded chunks per kt-slice (7.5 * 256)
#define BT_BYTES  (BT_CH_PAD * 16)
__global__ __launch_bounds__(256) void k0_prep(
    const float* __restrict__ Wq, const float* __restrict__ Wk,
    const float* __restrict__ Wv, const float* __restrict__ Wg,
    unsigned short* __restrict__ Wt)
{
  const int n = blockIdx.x;      // 0..207
  #pragma unroll
  for (int j = 0; j < 5; ++j) {
    int idx = threadIdx.x + 256 * j;   // 0..1151 : 16 kt * 72 shorts
    if (idx < 1152) {
      int kt = idx / 72;
      int r  = idx - kt * 72;
      int c = r >> 3, e = r & 7;
      float v = 0.f;
      if (c < 8 && n < 193) {
        int k = kt * 64 + c * 8 + e;
        v = (n < 64)  ? Wq[(size_t)k * 64 + n]
          : (n < 128) ? Wk[(size_t)k * 64 + (n - 64)]
          : (n < 192) ? Wv[(size_t)k * 64 + (n - 128)]
                      : Wg[k];
      }
      Wt[((size_t)kt * BT_CH_PAD + (size_t)n * 9 + c) * 8 + e] = f2bf(v);
    }
  }
}

// ---------------- Kernel 1: MFMA fused q,k,v,gate projection ----------------
// v3b (m97-style): 64-row blocks, grid 512, 3 blocks/CU.
//  - A staged global->LDS via global_load_lds (linear LDS dest, per-lane
//    pre-permuted global source; row padded to 272B -> conflict-free frags).
//  - B staged as a perfectly LINEAR 30720B copy of k0's pre-arranged slice.
//  - Gate = 13th N-tile (col 192 = Wg): no separate gate path.
//  - Epilogue transposes accs through LDS -> coalesced float4 stores (kills
//    the 5x write amplification R1 showed: WRITE_SIZE 127MB vs 24MB logical).
#define K1_ROWS 64
#define A_STRIDE 272          // 64 fp32 + 16B pad
#define B_STRIDE 144          // 64 bf16 + 16B pad

__global__ __launch_bounds__(256, 3) void k1_qkvg_mfma(
    const float* __restrict__ x, const unsigned short* __restrict__ Wt,
    const float* __restrict__ bg,
    float* __restrict__ q_ws, float* __restrict__ a_ws, float* __restrict__ b_ws)
{
  __shared__ __align__(16) unsigned char AsB[K1_ROWS * A_STRIDE];   // 17408 B
  __shared__ __align__(16) unsigned char BsB[BT_BYTES];             // 30720 B

  const int tid  = threadIdx.x;
  const int lane = tid & 63;
  const int w    = tid >> 6;        // wave 0..3 -> rows 16w..16w+15
  const int quad = lane >> 4;
  const int l15  = lane & 15;
  const int row0 = blockIdx.x * K1_ROWS;

  const unsigned char* xb  = (const unsigned char*)(x + (size_t)row0 * D_SZ);
  const unsigned char* wtb = (const unsigned char*)Wt;

  // Per-thread A-staging global pointers (chunk ci = i*256+tid).
  // A tile = 64 rows x 17 chunks (chunk 16 = pad -> reads row base, unused).
  const unsigned char* xA[5];
  #pragma unroll
  for (int i = 0; i < 5; ++i) {
    int ci  = i * 256 + tid;
    int row = ci / 17;
    int c17 = ci - row * 17;
    xA[i] = xb + (size_t)row * 4096 + (c17 < 16 ? c17 * 16 : 0);
  }

  f32x4 acc[13];
  #pragma unroll
  for (int tn = 0; tn < 13; ++tn) acc[tn] = (f32x4){0.f, 0.f, 0.f, 0.f};

  for (int t = 0; t < 16; ++t) {
    // ---- stage A: 64 x (64 fp32 + pad) = 1088 chunks ----
    #pragma unroll
    for (int i = 0; i < 4; ++i)
      gl2lds16(xA[i] + (size_t)t * 256, AsB + (i * 256 + tid) * 16);
    if (tid < 64)                                      // wave 0, fully active
      gl2lds16(xA[4] + (size_t)t * 256, AsB + (4 * 256 + tid) * 16);
    // ---- stage B: linear 30720B copy of kt-slice (1920 chunks) ----
    const unsigned char* wt_t = wtb + (size_t)t * BT_BYTES;
    #pragma unroll
    for (int i = 0; i < 7; ++i)
      gl2lds16(wt_t + (i * 256 + tid) * 16, BsB + (i * 256 + tid) * 16);
    if (tid < 128)                                     // waves 0-1, fully active
      gl2lds16(wt_t + (7 * 256 + tid) * 16, BsB + (7 * 256 + tid) * 16);

    __syncthreads();   // drains vmcnt -> staged data visible

    // ---- A frags: fp32 -> bf16 in-register ----
    bf16x8 af[2];
    #pragma unroll
    for (int kt = 0; kt < 2; ++kt) {
      const unsigned char* ap = AsB + (16 * w + l15) * A_STRIDE + kt * 128 + quad * 32;
      float4 lo = *reinterpret_cast<const float4*>(ap);
      float4 hi = *reinterpret_cast<const float4*>(ap + 16);
      uint4 p;
      p.x = (unsigned)f2bf(lo.x) | ((unsigned)f2bf(lo.y) << 16);
      p.y = (unsigned)f2bf(lo.z) | ((unsigned)f2bf(lo.w) << 16);
      p.z = (unsigned)f2bf(hi.x) | ((unsigned)f2bf(hi.y) << 16);
      p.w = (unsigned)f2bf(hi.z) | ((unsigned)f2bf(hi.w) << 16);
      af[kt] = *reinterpret_cast<bf16x8*>(&p);
    }
    // ---- MFMA: 13 n-tiles x 2 k-halves ----
    #pragma unroll
    for (int tn = 0; tn < 13; ++tn) {
      #pragma unroll
      for (int kt = 0; kt < 2; ++kt) {
        bf16x8 bf = *reinterpret_cast<const bf16x8*>(
            BsB + (tn * 16 + l15) * B_STRIDE + kt * 64 + quad * 16);
        acc[tn] = __builtin_amdgcn_mfma_f32_16x16x32_bf16(af[kt], bf, acc[tn], 0, 0, 0);
      }
    }
    __syncthreads();   // all frag reads done before next stage overwrites
  }

  // ---- gate: col 192 lives at l15==0 lanes of acc[12]; broadcast per quad ----
  const float bg0 = bg[0];
  float g4[4];
  #pragma unroll
  for (int r = 0; r < 4; ++r) {
    float gv = __shfl(acc[12][r], lane & 48);   // lane quad*16 holds C[quad*4+r][192]
    g4[r] = sigmoid_f(gv + bg0);
  }

  // ---- epilogue: transpose via LDS, coalesced float4 stores ----
  float (*T)[68] = (float(*)[68])AsB;   // 64*68*4 = 17408 = sizeof(AsB)
  const int erow = tid >> 2, eq4 = tid & 3;
  #pragma unroll
  for (int p = 0; p < 3; ++p) {
    float* dst = (p == 0) ? q_ws : (p == 1) ? a_ws : b_ws;
    #pragma unroll
    for (int tn4 = 0; tn4 < 4; ++tn4) {
      #pragma unroll
      for (int r = 0; r < 4; ++r) {
        float v = acc[p * 4 + tn4][r];
        if (p > 0) v *= g4[r];
        T[16 * w + quad * 4 + r][tn4 * 16 + l15] = v;
      }
    }
    __syncthreads();
    float4 vv[4];
    #pragma unroll
    for (int j = 0; j < 4; ++j)
      vv[j] = *reinterpret_cast<float4*>(&T[erow][eq4 * 16 + 4 * j]);
    #pragma unroll
    for (int j = 0; j < 4; ++j)
      *reinterpret_cast<float4*>(&dst[(size_t)(row0 + erow) * 64 + eq4 * 16 + 4 * j]) = vv[j];
    if (p < 2) __syncthreads();
  }
}

// ---------------- Kernel 2: per-chunk state delta ----------------
__global__ __launch_bounds__(256) void k2_delta(
    const float* __restrict__ a_ws, const float* __restrict__ b_ws,
    const float* __restrict__ dp, float* __restrict__ dS)
{
  __shared__ float Aa[64][64];
  __shared__ float Bc[64][64];
  __shared__ float pw[64];
  const int tid = threadIdx.x;
  const int bc = blockIdx.x;                       // b*64 + c
  const int rowbase = (bc >> 6) * L_SZ + (bc & 63) * CHUNK;
  const int s = tid >> 2, m0 = (tid & 3) * 16;
  #pragma unroll
  for (int j = 0; j < 4; ++j) {
    *reinterpret_cast<float4*>(&Aa[s][m0 + 4*j]) =
        *reinterpret_cast<const float4*>(&a_ws[(size_t)(rowbase + s) * 64 + m0 + 4*j]);
    *reinterpret_cast<float4*>(&Bc[s][m0 + 4*j]) =
        *reinterpret_cast<const float4*>(&b_ws[(size_t)(rowbase + s) * 64 + m0 + 4*j]);
  }
  if (tid < 64) pw[tid] = powf(decay_of(dp), (float)(63 - tid));
  __syncthreads();
  const int d0 = tid >> 2, e0 = (tid & 3) * 16;
  float4 o0 = make_float4(0,0,0,0), o1 = o0, o2 = o0, o3 = o0;
  for (int ss = 0; ss < 64; ++ss) {
    float wa = pw[ss] * Aa[ss][d0];
    float4 b0 = *reinterpret_cast<float4*>(&Bc[ss][e0+0]);
    float4 b1 = *reinterpret_cast<float4*>(&Bc[ss][e0+4]);
    float4 b2 = *reinterpret_cast<float4*>(&Bc[ss][e0+8]);
    float4 b3 = *reinterpret_cast<float4*>(&Bc[ss][e0+12]);
    FMA4(o0, wa, b0); FMA4(o1, wa, b1); FMA4(o2, wa, b2); FMA4(o3, wa, b3);
  }
  float* dst = &dS[((size_t)bc << 12) + d0 * 64 + e0];
  *reinterpret_cast<float4*>(dst + 0)  = o0;
  *reinterpret_cast<float4*>(dst + 4)  = o1;
  *reinterpret_cast<float4*>(dst + 8)  = o2;
  *reinterpret_cast<float4*>(dst + 12) = o3;
}

// ---------------- Kernel 3: elementwise scan over chunks ----------------
__global__ __launch_bounds__(256) void k3_scan(
    const float* __restrict__ dS, const float* __restrict__ dp,
    float* __restrict__ Sst, float* __restrict__ sfin)
{
  const int g = blockIdx.x * 256 + threadIdx.x;   // 0..32767
  const int b = g >> 12;
  const int de = g & 4095;
  const float dC = powf(decay_of(dp), 64.0f);
  const size_t base = ((size_t)(b * 64) << 12) + de;
  float d[NCHUNK];
  #pragma unroll
  for (int c = 0; c < NCHUNK; ++c) d[c] = dS[base + ((size_t)c << 12)];
  float s = 0.f;
  #pragma unroll
  for (int c = 0; c < NCHUNK; ++c) {
    Sst[base + ((size_t)c << 12)] = s;
    s = dC * s + d[c];
  }
  sfin[((size_t)b << 12) + de] = s;
}

// ---------------- Kernel 4: intra-chunk outputs ----------------
__global__ __launch_bounds__(256) void k4_intra(
    const float* __restrict__ q_ws, const float* __restrict__ a_ws,
    const float* __restrict__ b_ws, const float* __restrict__ Sst,
    const float* __restrict__ dp, float* __restrict__ outs)
{
  __shared__ float Qs[64][68];   // padded (col reads)
  __shared__ float Ps[64][68];   // holds A^T during phase 1, then P
  __shared__ float Bs[64][64];
  __shared__ float S0s[64][64];
  __shared__ float pw[65];
  const int tid = threadIdx.x;
  const int bc = blockIdx.x;
  const int rowbase = (bc >> 6) * L_SZ + (bc & 63) * CHUNK;
  const int s = tid >> 2, m0 = (tid & 3) * 16;
  #pragma unroll
  for (int j = 0; j < 4; ++j) {
    float4 qv = *reinterpret_cast<const float4*>(&q_ws[(size_t)(rowbase + s) * 64 + m0 + 4*j]);
    Qs[s][m0+4*j+0] = qv.x; Qs[s][m0+4*j+1] = qv.y; Qs[s][m0+4*j+2] = qv.z; Qs[s][m0+4*j+3] = qv.w;
    float4 av = *reinterpret_cast<const float4*>(&a_ws[(size_t)(rowbase + s) * 64 + m0 + 4*j]);
    Ps[m0+4*j+0][s] = av.x; Ps[m0+4*j+1][s] = av.y; Ps[m0+4*j+2][s] = av.z; Ps[m0+4*j+3][s] = av.w;
    float4 bv = *reinterpret_cast<const float4*>(&b_ws[(size_t)(rowbase + s) * 64 + m0 + 4*j]);
    *reinterpret_cast<float4*>(&Bs[s][m0+4*j]) = bv;
    float4 sv = *reinterpret_cast<const float4*>(&Sst[((size_t)bc << 12) + tid*16 + 4*j]);
    *reinterpret_cast<float4*>(&(&S0s[0][0])[tid*16 + 4*j]) = sv;
  }
  if (tid < 65) pw[tid] = powf(decay_of(dp), (float)tid);
  __syncthreads();

  const int t0 = tid >> 2, c0 = (tid & 3) * 16;  // this thread: row t0, cols c0..c0+15
  float4 r0 = make_float4(0,0,0,0), r1 = r0, r2 = r0, r3 = r0;
  for (int m = 0; m < 64; ++m) {
    float qv = Qs[t0][m];
    float4 a0 = *reinterpret_cast<float4*>(&Ps[m][c0+0]);
    float4 a1 = *reinterpret_cast<float4*>(&Ps[m][c0+4]);
    float4 a2 = *reinterpret_cast<float4*>(&Ps[m][c0+8]);
    float4 a3 = *reinterpret_cast<float4*>(&Ps[m][c0+12]);
    FMA4(r0, qv, a0); FMA4(r1, qv, a1); FMA4(r2, qv, a2); FMA4(r3, qv, a3);
  }
  float rr[16] = {r0.x,r0.y,r0.z,r0.w, r1.x,r1.y,r1.z,r1.w,
                  r2.x,r2.y,r2.z,r2.w, r3.x,r3.y,r3.z,r3.w};
  __syncthreads();  // everyone done reading A^T
  #pragma unroll
  for (int j = 0; j < 16; ++j) {
    const int sidx = c0 + j;
    Ps[t0][sidx] = (sidx <= t0) ? rr[j] * pw[t0 - sidx] : 0.f;
  }
  __syncthreads();

  float4 o0 = make_float4(0,0,0,0), o1 = o0, o2 = o0, o3 = o0;
  for (int m = 0; m < 64; ++m) {
    float qv = Qs[t0][m];
    float4 v0 = *reinterpret_cast<float4*>(&S0s[m][c0+0]);
    float4 v1 = *reinterpret_cast<float4*>(&S0s[m][c0+4]);
    float4 v2 = *reinterpret_cast<float4*>(&S0s[m][c0+8]);
    float4 v3 = *reinterpret_cast<float4*>(&S0s[m][c0+12]);
    FMA4(o0, qv, v0); FMA4(o1, qv, v1); FMA4(o2, qv, v2); FMA4(o3, qv, v3);
  }
  const float dsc = pw[t0 + 1];
  SCALE4(o0, dsc); SCALE4(o1, dsc); SCALE4(o2, dsc); SCALE4(o3, dsc);
  for (int ss = 0; ss < 64; ++ss) {
    float pv = Ps[t0][ss];
    float4 b0 = *reinterpret_cast<float4*>(&Bs[ss][c0+0]);
    float4 b1 = *reinterpret_cast<float4*>(&Bs[ss][c0+4]);
    float4 b2 = *reinterpret_cast<float4*>(&Bs[ss][c0+8]);
    float4 b3 = *reinterpret_cast<float4*>(&Bs[ss][c0+12]);
    FMA4(o0, pv, b0); FMA4(o1, pv, b1); FMA4(o2, pv, b2); FMA4(o3, pv, b3);
  }
  float* dst = &outs[(size_t)(rowbase + t0) * 64 + c0];
  *reinterpret_cast<float4*>(dst + 0)  = o0;
  *reinterpret_cast<float4*>(dst + 4)  = o1;
  *reinterpret_cast<float4*>(dst + 8)  = o2;
  *reinterpret_cast<float4*>(dst + 12) = o3;
}

// ---------------- Kernel 5: output projection ----------------
// Os stride 65 (== 1 mod 32): the scalar a-reads go from 2-way-conflicted
// 4-address groups to 4 distinct banks.
__global__ __launch_bounds__(256) void k5_proj(
    const float* __restrict__ outs, const float* __restrict__ Wo,
    const float* __restrict__ bo, float* __restrict__ y)
{
  __shared__ float Os[64][65];
  __shared__ float Ws[64][64];
  const int tid = threadIdx.x;
  const int tx = tid & 15, ty = tid >> 4;
  const int row0 = blockIdx.x * 64;
  const int n0 = blockIdx.y * 64;
  const int s = tid >> 2, m0 = (tid & 3) * 16;
  #pragma unroll
  for (int j = 0; j < 4; ++j) {
    float4 ov = *reinterpret_cast<const float4*>(&outs[(size_t)(row0 + s) * 64 + m0 + 4*j]);
    Os[s][m0+4*j+0] = ov.x; Os[s][m0+4*j+1] = ov.y; Os[s][m0+4*j+2] = ov.z; Os[s][m0+4*j+3] = ov.w;
    float4 wv = *reinterpret_cast<const float4*>(&Wo[(size_t)s * D_SZ + n0 + m0 + 4*j]);
    *reinterpret_cast<float4*>(&Ws[s][m0+4*j]) = wv;
  }
  __syncthreads();
  float4 acc[4];
  #pragma unroll
  for (int r = 0; r < 4; ++r) acc[r] = make_float4(0,0,0,0);
  for (int kk = 0; kk < 64; ++kk) {
    float a0 = Os[4*ty+0][kk];
    float a1 = Os[4*ty+1][kk];
    float a2 = Os[4*ty+2][kk];
    float a3 = Os[4*ty+3][kk];
    float4 w = *reinterpret_cast<float4*>(&Ws[kk][4*tx]);
    FMA4(acc[0], a0, w); FMA4(acc[1], a1, w); FMA4(acc[2], a2, w); FMA4(acc[3], a3, w);
  }
  float4 bv = *reinterpret_cast<const float4*>(&bo[n0 + 4*tx]);
  #pragma unroll
  for (int r = 0; r < 4; ++r) {
    float4 res;
    res.x = acc[r].x + bv.x; res.y = acc[r].y + bv.y;
    res.z = acc[r].z + bv.z; res.w = acc[r].w + bv.w;
    *reinterpret_cast<float4*>(&y[(size_t)(row0 + 4*ty + r) * D_SZ + n0 + 4*tx]) = res;
  }
}

// ---------------- Launcher ----------------
extern "C" void kernel_launch(void* const* d_in, const int* in_sizes, int n_in,
                              void* d_out, int out_size, void* d_ws, size_t ws_size,
                              hipStream_t stream) {
  (void)in_sizes; (void)n_in; (void)out_size; (void)ws_size;
  const float* x  = (const float*)d_in[0];
  const float* Wq = (const float*)d_in[1];
  const float* Wk = (const float*)d_in[2];
  const float* Wv = (const float*)d_in[3];
  const float* Wo = (const float*)d_in[4];
  const float* bo = (const float*)d_in[5];
  const float* Wg = (const float*)d_in[6];
  const float* bg = (const float*)d_in[7];
  const float* dp = (const float*)d_in[8];

  float* y    = (float*)d_out;                       // (8,4096,1024)
  float* sfin = y + (size_t)B_SZ * L_SZ * D_SZ;      // (8,64,64)

  float* ws   = (float*)d_ws;
  const size_t SEG = (size_t)ROWS * M_SZ;            // 2,097,152 floats
  float* q_ws = ws;
  float* a_ws = q_ws + SEG;
  float* b_ws = a_ws + SEG;
  float* dS   = b_ws + SEG;   // (B*NC, 64,64)
  float* Sst  = dS   + SEG;   // chunk-start states
  float* outs = Sst  + SEG;   // (32768, 64)
  // Wt (bf16, 16 slices x 30720B = 480KB) aliases the head of `outs`: dead
  // after k1 reads it, before k4 writes outs. Rewritten every call.
  unsigned short* Wt = (unsigned short*)outs;

  k0_prep<<<dim3(208), dim3(256), 0, stream>>>(Wq, Wk, Wv, Wg, Wt);
  k1_qkvg_mfma<<<dim3(ROWS / K1_ROWS), dim3(256), 0, stream>>>(x, Wt, bg, q_ws, a_ws, b_ws);
  k2_delta<<<dim3(B_SZ * NCHUNK), dim3(256), 0, stream>>>(a_ws, b_ws, dp, dS);
  k3_scan<<<dim3((B_SZ * M_SZ * M_SZ) / 256), dim3(256), 0, stream>>>(dS, dp, Sst, sfin);
  k4_intra<<<dim3(B_SZ * NCHUNK), dim3(256), 0, stream>>>(q_ws, a_ws, b_ws, Sst, dp, outs);
  k5_proj<<<dim3(ROWS / 64, D_SZ / 64), dim3(256), 0, stream>>>(outs, Wo, bo, y);
}